// Round 2
// 66.095 us; speedup vs baseline: 1.0194x; 1.0194x over previous
//
#include <hip/hip_runtime.h>
#include <cstdint>

// QuLinear: 20-qubit circuit -> marginal probs of 10 MSB qubits (1024 floats).
//
// Round-4 design (resubmitted after infra failure; source unchanged):
// same verified pipeline as round-3 (4 waves per l-value, 4 amps/lane,
// butterfly split lane/reg/wave), with two changes driven by the profile
// (top-5 dispatches are all the harness's 268MB ws-poison fill at 39.4us
// => our controllable budget is dispatch count + kernel VALU):
//   1. No memset + no atomics: each block plain-stores its 1024-float row
//      ws[b][h] (coalesced); a second kernel column-reduces 1024 rows -> out.
//      Stream order replaces zero-init. 2 dispatches instead of 3.
//   2. Pair product tables: P[p][j] = v[2p][j&1]*v[2p+1][j>>1] in LDS.
//      The 20-qubit per-amp product becomes 10 indexed ds_read_b64 + cmul
//      (conflict-free: 4 entries span 32B = disjoint bank pairs), halving
//      the synthesis VALU count.

#define NQ      20
#define NPART   10
#define NH      1024
#define BLOCK   256
#define NPAIR   10

struct MaskArg { uint32_t m[NQ]; };

__device__ __forceinline__ float2 cmul(float2 a, float2 b) {
    return make_float2(fmaf(a.x, b.x, -a.y * b.y), fmaf(a.x, b.y, a.y * b.x));
}
__device__ __forceinline__ float2 cadd(float2 a, float2 b) {
    return make_float2(a.x + b.x, a.y + b.y);
}

__global__ __launch_bounds__(BLOCK, 4) void qulinear_kernel(
        const float* __restrict__ x, const float* __restrict__ w,
        float* __restrict__ ws, MaskArg masks) {
    __shared__ float2 v[NQ][2];          // per-qubit encoding 2-vectors
    __shared__ float2 U[NPART][2][2];    // Rx*Rz*Rx for measured qubits
    __shared__ float2 P[NPAIR][4];       // qubit-pair product tables
    __shared__ float2 ex[4][4][64];      // cross-wave exchange (8 KB)

    const int tid = threadIdx.x;

    // ---- block setup ----
    if (tid < NQ) {
        float xq = x[tid];
        float th = atanf(xq);
        float ph = atanf(xq * xq);
        float c, s, cp, sp;
        __sincosf(0.5f * th, &s, &c);
        __sincosf(0.5f * ph, &sp, &cp);
        float a = (c - s) * 0.70710678118654752f;
        float b = (c + s) * 0.70710678118654752f;
        v[tid][0] = make_float2(a * cp, -a * sp);
        v[tid][1] = make_float2(b * cp,  b * sp);
    }
    if (tid < NPART) {
        const float WM = 0.63245553203367590f;   // sqrt(2/5)
        float a0 = w[3 * tid + 0] * WM;
        float a1 = w[3 * tid + 1] * WM;
        float a2 = w[3 * tid + 2] * WM;
        float c0, s0, c1, s1, c2, s2;
        __sincosf(0.5f * a0, &s0, &c0);
        __sincosf(0.5f * a1, &s1, &c1);
        __sincosf(0.5f * a2, &s2, &c2);
        float2 e0 = make_float2(c1, -s1), e1 = make_float2(c1, s1);
        float2 m00 = cmul(e0, make_float2(c0, 0.f));
        float2 m01 = cmul(e0, make_float2(0.f, -s0));
        float2 m10 = cmul(e1, make_float2(0.f, -s0));
        float2 m11 = cmul(e1, make_float2(c0, 0.f));
        float2 r00 = make_float2(c2, 0.f), r01 = make_float2(0.f, -s2);
        U[tid][0][0] = cadd(cmul(r00, m00), cmul(r01, m10));
        U[tid][0][1] = cadd(cmul(r00, m01), cmul(r01, m11));
        U[tid][1][0] = cadd(cmul(r01, m00), cmul(r00, m10));
        U[tid][1][1] = cadd(cmul(r01, m01), cmul(r00, m11));
    }
    __syncthreads();
    if (tid < 4 * NPAIR) {
        int p = tid >> 2, j = tid & 3;
        // idx bit0 selects qubit 2p, bit1 selects qubit 2p+1
        P[p][j] = cmul(v[2 * p][j & 1], v[2 * p + 1][(j >> 1) & 1]);
    }
    __syncthreads();

    const int wq   = tid >> 6;           // wave index = h-bits 8..9
    const int lane = tid & 63;           // h-bits 0..5
    const uint32_t l = blockIdx.x;

    // ---- per-lane packed parity words ----
    // y-bit map: l -> 0..9, lane -> 10..15, r -> 16..17, wq -> 18..19
    const uint32_t y0 = ((uint32_t)lane << NPART) | l | ((uint32_t)wq << 18);
    uint32_t sbase = 0, d16 = 0, d17 = 0;
    #pragma unroll
    for (int q = 0; q < NQ; ++q) {
        sbase |= (uint32_t)(__popc(masks.m[q] & y0) & 1) << q;
        d16   |= (uint32_t)((masks.m[q] >> 16) & 1u) << q;
        d17   |= (uint32_t)((masks.m[q] >> 17) & 1u) << q;
    }
    uint32_t s[4];
    s[0] = sbase; s[1] = sbase ^ d16; s[2] = sbase ^ d17; s[3] = sbase ^ d16 ^ d17;

    // ---- wave-uniform row of the 4x4 cross-wave matrix G = U0 (x) U1 ----
    float2 g[4];
    #pragma unroll
    for (int j = 0; j < 4; ++j)
        g[j] = cmul(U[0][wq >> 1][j >> 1], U[1][wq & 1][j & 1]);

    // ---- synthesize psi via pair tables: amp[r] = prod_p P[p][2-bit sel] ----
    float2 amp[4];
    #pragma unroll
    for (int r = 0; r < 4; ++r) amp[r] = P[0][s[r] & 3];

    #pragma unroll
    for (int p = 1; p < NPAIR; ++p) {
        #pragma unroll
        for (int r = 0; r < 4; ++r) {
            int idx = (s[r] >> (2 * p)) & 3;
            amp[r] = cmul(amp[r], P[p][idx]);
        }
    }

    // ---- in-register stages: h-bit 6 (U[3]), h-bit 7 (U[2]) ----
    {
        float2 g00 = U[3][0][0], g01 = U[3][0][1], g10 = U[3][1][0], g11 = U[3][1][1];
        float2 a, b;
        a = amp[0]; b = amp[1];
        amp[0] = cadd(cmul(g00, a), cmul(g01, b));
        amp[1] = cadd(cmul(g10, a), cmul(g11, b));
        a = amp[2]; b = amp[3];
        amp[2] = cadd(cmul(g00, a), cmul(g01, b));
        amp[3] = cadd(cmul(g10, a), cmul(g11, b));
    }
    {
        float2 g00 = U[2][0][0], g01 = U[2][0][1], g10 = U[2][1][0], g11 = U[2][1][1];
        float2 a, b;
        a = amp[0]; b = amp[2];
        amp[0] = cadd(cmul(g00, a), cmul(g01, b));
        amp[2] = cadd(cmul(g10, a), cmul(g11, b));
        a = amp[1]; b = amp[3];
        amp[1] = cadd(cmul(g00, a), cmul(g01, b));
        amp[3] = cadd(cmul(g10, a), cmul(g11, b));
    }

    // ---- shfl stages: h-bits 0..5 (U[9]..U[4]) ----
    #pragma unroll
    for (int p = 0; p < 6; ++p) {
        const int lm = 1 << p;
        const bool bit = (lane & lm) != 0;
        float2 g00 = U[9 - p][0][0], g01 = U[9 - p][0][1];
        float2 g10 = U[9 - p][1][0], g11 = U[9 - p][1][1];
        float2 ga = bit ? g11 : g00;
        float2 gb = bit ? g10 : g01;
        #pragma unroll
        for (int r = 0; r < 4; ++r) {
            float2 mine = amp[r];
            float2 oth = make_float2(__shfl_xor(mine.x, lm, 64),
                                     __shfl_xor(mine.y, lm, 64));
            amp[r] = cadd(cmul(ga, mine), cmul(gb, oth));
        }
    }

    // ---- cross-wave stage: h-bits 8..9 via fused 4x4 LDS combine ----
    #pragma unroll
    for (int r = 0; r < 4; ++r) ex[wq][r][lane] = amp[r];
    __syncthreads();
    #pragma unroll
    for (int r = 0; r < 4; ++r) {
        float2 acc = cmul(g[0], ex[0][r][lane]);
        acc = cadd(acc, cmul(g[1], ex[1][r][lane]));
        acc = cadd(acc, cmul(g[2], ex[2][r][lane]));
        acc = cadd(acc, cmul(g[3], ex[3][r][lane]));
        amp[r] = acc;
    }

    // ---- |amp|^2 -> this block's own row (plain coalesced stores) ----
    float* wsp = ws + (size_t)blockIdx.x * NH;
    #pragma unroll
    for (int r = 0; r < 4; ++r) {
        int h = (wq << 8) | (r << 6) | lane;
        wsp[h] = fmaf(amp[r].x, amp[r].x, amp[r].y * amp[r].y);
    }
}

// Column-reduce 1024 rows of ws into out. 64 blocks x 16 h each.
// thread t: hl = t&15, row-group rg = t>>4 owns 64 contiguous rows.
__global__ __launch_bounds__(BLOCK) void reduce_kernel(
        const float* __restrict__ ws, float* __restrict__ out) {
    __shared__ float red[16][17];
    const int g  = blockIdx.x;
    const int hl = threadIdx.x & 15;
    const int rg = threadIdx.x >> 4;
    const float* p = ws + (size_t)(rg * 64) * NH + g * 16 + hl;
    float acc = 0.f;
    #pragma unroll
    for (int k = 0; k < 64; ++k) acc += p[(size_t)k * NH];
    red[rg][hl] = acc;
    __syncthreads();
    if (threadIdx.x < 16) {
        float a = 0.f;
        #pragma unroll
        for (int i = 0; i < 16; ++i) a += red[i][threadIdx.x];
        out[g * 16 + threadIdx.x] = a;
    }
}

extern "C" void kernel_launch(void* const* d_in, const int* in_sizes, int n_in,
                              void* d_out, int out_size, void* d_ws, size_t ws_size,
                              hipStream_t stream) {
    const float* x = (const float*)d_in[0];   // (1, 20) f32
    const float* w = (const float*)d_in[1];   // (60,)   f32
    float* out = (float*)d_out;               // (1, 1024) f32

    // Compose the CNOT block into 20 GF(2) row-masks over the index bits.
    // state_after[y] = state_enc[B y]; reverse-order rule: M[target] ^= M[control].
    MaskArg ma;
    {
        uint32_t M[NQ];
        for (int q = 0; q < NQ; ++q) M[q] = 1u << q;
        for (int q = NQ - 1; q >= 0; --q) {
            M[(q + 2) % NQ] ^= M[q];
            M[(q + 1) % NQ] ^= M[q];
        }
        for (int q = 0; q < NQ; ++q) {        // qubit j -> index bit (19-j)
            uint32_t im = 0;
            for (int j = 0; j < NQ; ++j)
                if ((M[q] >> j) & 1) im |= 1u << (NQ - 1 - j);
            ma.m[q] = im;
        }
    }

    qulinear_kernel<<<NH, BLOCK, 0, stream>>>(x, w, (float*)d_ws, ma);
    reduce_kernel<<<NH / 16, BLOCK, 0, stream>>>((const float*)d_ws, out);
}

// Round 4
// 65.712 us; speedup vs baseline: 1.0253x; 1.0058x over previous
//
#include <hip/hip_runtime.h>
#include <cstdint>

// QuLinear: 20-qubit circuit -> marginal probs of 10 MSB qubits (1024 floats).
//
// Round-6 design: revert to the VERIFIED 2-dispatch structure (round-4,
// 66.1us passed) after the cooperative single-dispatch experiment failed
// (unchecked coop launch at exact capacity + cross-XCD visibility of plain
// stores after grid.sync are each sufficient to explain the failure; the
// measured value of a removed dispatch is only ~1.3us — not worth the risk).
//
// Structure: 4 waves per l-value, 4 amps/lane; butterfly over h split as
// lane bits (6 shfl stages) / reg bits (2 in-reg stages) / wave bits
// (fused 4x4 LDS combine); block stores its own 1024-float row ws[b][:]
// (coalesced, no atomics, no memset); kernel2 column-reduces 1024 rows.
//
// New this round (kernel1 VALU cuts, ~25% of per-thread compute):
//   1. Quad tables Q[g][16] = v[4g](x)v[4g+1](x)v[4g+2](x)v[4g+3]:
//      synthesis = 5 indexed ds_read_b64 + 4 cmul per amp. The 16 entries
//      of a table span 16 disjoint bank-pairs -> conflict-free; equal
//      indices broadcast free.
//   2. Parity factorization over disjoint y-fields:
//      s(y) bit q = parity(m[q] & y),  y = l | lane<<10 | r<<16 | wq<<18
//      = tl (block-uniform, SALU) ^ Tl[lane] (64-entry LDS table built by
//        wave 1 during setup) ^ thi[wq*4+r] (host-computed kernarg table).
//      Replaces a 20x ~6-VALU popcount loop on the main path.

#define NQ      20
#define NPART   10
#define NH      1024
#define BLOCK   256
#define NQUAD   5

struct MaskArg {
    uint32_t m[NQ];      // GF(2) row-masks over index bits
    uint32_t thi[16];    // parity of m[q] & ((wq<<18)|(r<<16)), idx = wq*4+r
};

__device__ __forceinline__ float2 cmul(float2 a, float2 b) {
    return make_float2(fmaf(a.x, b.x, -a.y * b.y), fmaf(a.x, b.y, a.y * b.x));
}
__device__ __forceinline__ float2 cadd(float2 a, float2 b) {
    return make_float2(a.x + b.x, a.y + b.y);
}

__global__ __launch_bounds__(BLOCK, 4) void qulinear_kernel(
        const float* __restrict__ x, const float* __restrict__ w,
        float* __restrict__ ws, MaskArg masks) {
    __shared__ float2 v[NQ][2];          // per-qubit encoding 2-vectors
    __shared__ float2 U[NPART][2][2];    // Rx*Rz*Rx for measured qubits
    __shared__ float2 Q[NQUAD][16];      // 4-qubit product tables (640 B)
    __shared__ uint32_t Tl[64];          // lane-field parity table (256 B)
    __shared__ float2 ex[4][4][64];      // cross-wave exchange (8 KB)

    const int tid = threadIdx.x;

    // ---- block setup: wave 0 builds v,U; wave 1 builds Tl ----
    if (tid < NQ) {
        float xq = x[tid];
        float th = atanf(xq);
        float ph = atanf(xq * xq);
        float c, s, cp, sp;
        __sincosf(0.5f * th, &s, &c);
        __sincosf(0.5f * ph, &sp, &cp);
        float a = (c - s) * 0.70710678118654752f;
        float b = (c + s) * 0.70710678118654752f;
        v[tid][0] = make_float2(a * cp, -a * sp);
        v[tid][1] = make_float2(b * cp,  b * sp);
    }
    if (tid < NPART) {
        const float WM = 0.63245553203367590f;   // sqrt(2/5)
        float a0 = w[3 * tid + 0] * WM;
        float a1 = w[3 * tid + 1] * WM;
        float a2 = w[3 * tid + 2] * WM;
        float c0, s0, c1, s1, c2, s2;
        __sincosf(0.5f * a0, &s0, &c0);
        __sincosf(0.5f * a1, &s1, &c1);
        __sincosf(0.5f * a2, &s2, &c2);
        float2 e0 = make_float2(c1, -s1), e1 = make_float2(c1, s1);
        float2 m00 = cmul(e0, make_float2(c0, 0.f));
        float2 m01 = cmul(e0, make_float2(0.f, -s0));
        float2 m10 = cmul(e1, make_float2(0.f, -s0));
        float2 m11 = cmul(e1, make_float2(c0, 0.f));
        float2 r00 = make_float2(c2, 0.f), r01 = make_float2(0.f, -s2);
        U[tid][0][0] = cadd(cmul(r00, m00), cmul(r01, m10));
        U[tid][0][1] = cadd(cmul(r00, m01), cmul(r01, m11));
        U[tid][1][0] = cadd(cmul(r01, m00), cmul(r00, m10));
        U[tid][1][1] = cadd(cmul(r01, m01), cmul(r00, m11));
    }
    if (tid >= 64 && tid < 128) {
        const uint32_t yl = (uint32_t)(tid - 64) << NPART;   // lane field
        uint32_t t = 0;
        #pragma unroll
        for (int q = 0; q < NQ; ++q)
            t |= (uint32_t)(__popc(masks.m[q] & yl) & 1) << q;
        Tl[tid - 64] = t;
    }
    __syncthreads();
    if (tid < 16 * NQUAD) {
        int g = tid >> 4, j = tid & 15;   // bit i of j selects qubit 4g+i
        Q[g][j] = cmul(cmul(v[4 * g + 0][j & 1],        v[4 * g + 1][(j >> 1) & 1]),
                       cmul(v[4 * g + 2][(j >> 2) & 1], v[4 * g + 3][(j >> 3) & 1]));
    }
    __syncthreads();

    const int wq   = tid >> 6;           // wave index = h-bits 8..9
    const int lane = tid & 63;           // h-bits 0..5
    const uint32_t l = blockIdx.x;

    // ---- parity words via factorized tables ----
    // block-uniform l-field parity (all inputs SGPR -> scalarizable)
    uint32_t tl = 0;
    #pragma unroll
    for (int q = 0; q < NQ; ++q)
        tl |= (uint32_t)(__popc(masks.m[q] & l) & 1) << q;

    const uint32_t sbase = tl ^ Tl[lane];
    uint32_t s[4];
    #pragma unroll
    for (int r = 0; r < 4; ++r)
        s[r] = sbase ^ masks.thi[(wq << 2) | r];

    // ---- wave-uniform row of the 4x4 cross-wave matrix G = U0 (x) U1 ----
    float2 g[4];
    #pragma unroll
    for (int j = 0; j < 4; ++j)
        g[j] = cmul(U[0][wq >> 1][j >> 1], U[1][wq & 1][j & 1]);

    // ---- synthesize psi via quad tables: amp[r] = prod_g Q[g][4-bit sel] ----
    float2 amp[4];
    #pragma unroll
    for (int r = 0; r < 4; ++r) amp[r] = Q[0][s[r] & 15];

    #pragma unroll
    for (int p = 1; p < NQUAD; ++p) {
        #pragma unroll
        for (int r = 0; r < 4; ++r) {
            int idx = (s[r] >> (4 * p)) & 15;
            amp[r] = cmul(amp[r], Q[p][idx]);
        }
    }

    // ---- in-register stages: h-bit 6 (U[3]), h-bit 7 (U[2]) ----
    {
        float2 g00 = U[3][0][0], g01 = U[3][0][1], g10 = U[3][1][0], g11 = U[3][1][1];
        float2 a, b;
        a = amp[0]; b = amp[1];
        amp[0] = cadd(cmul(g00, a), cmul(g01, b));
        amp[1] = cadd(cmul(g10, a), cmul(g11, b));
        a = amp[2]; b = amp[3];
        amp[2] = cadd(cmul(g00, a), cmul(g01, b));
        amp[3] = cadd(cmul(g10, a), cmul(g11, b));
    }
    {
        float2 g00 = U[2][0][0], g01 = U[2][0][1], g10 = U[2][1][0], g11 = U[2][1][1];
        float2 a, b;
        a = amp[0]; b = amp[2];
        amp[0] = cadd(cmul(g00, a), cmul(g01, b));
        amp[2] = cadd(cmul(g10, a), cmul(g11, b));
        a = amp[1]; b = amp[3];
        amp[1] = cadd(cmul(g00, a), cmul(g01, b));
        amp[3] = cadd(cmul(g10, a), cmul(g11, b));
    }

    // ---- shfl stages: h-bits 0..5 (U[9]..U[4]) ----
    #pragma unroll
    for (int p = 0; p < 6; ++p) {
        const int lm = 1 << p;
        const bool bit = (lane & lm) != 0;
        float2 g00 = U[9 - p][0][0], g01 = U[9 - p][0][1];
        float2 g10 = U[9 - p][1][0], g11 = U[9 - p][1][1];
        float2 ga = bit ? g11 : g00;
        float2 gb = bit ? g10 : g01;
        #pragma unroll
        for (int r = 0; r < 4; ++r) {
            float2 mine = amp[r];
            float2 oth = make_float2(__shfl_xor(mine.x, lm, 64),
                                     __shfl_xor(mine.y, lm, 64));
            amp[r] = cadd(cmul(ga, mine), cmul(gb, oth));
        }
    }

    // ---- cross-wave stage: h-bits 8..9 via fused 4x4 LDS combine ----
    #pragma unroll
    for (int r = 0; r < 4; ++r) ex[wq][r][lane] = amp[r];
    __syncthreads();
    #pragma unroll
    for (int r = 0; r < 4; ++r) {
        float2 acc = cmul(g[0], ex[0][r][lane]);
        acc = cadd(acc, cmul(g[1], ex[1][r][lane]));
        acc = cadd(acc, cmul(g[2], ex[2][r][lane]));
        acc = cadd(acc, cmul(g[3], ex[3][r][lane]));
        amp[r] = acc;
    }

    // ---- |amp|^2 -> this block's own row (plain coalesced stores) ----
    float* wsp = ws + (size_t)blockIdx.x * NH;
    #pragma unroll
    for (int r = 0; r < 4; ++r) {
        int h = (wq << 8) | (r << 6) | lane;
        wsp[h] = fmaf(amp[r].x, amp[r].x, amp[r].y * amp[r].y);
    }
}

// Column-reduce 1024 rows of ws into out. 64 blocks x 16 h each.
// thread t: hl = t&15, row-group rg = t>>4 owns 64 contiguous rows.
__global__ __launch_bounds__(BLOCK) void reduce_kernel(
        const float* __restrict__ ws, float* __restrict__ out) {
    __shared__ float red[16][17];
    const int g  = blockIdx.x;
    const int hl = threadIdx.x & 15;
    const int rg = threadIdx.x >> 4;
    const float* p = ws + (size_t)(rg * 64) * NH + g * 16 + hl;
    float acc = 0.f;
    #pragma unroll
    for (int k = 0; k < 64; ++k) acc += p[(size_t)k * NH];
    red[rg][hl] = acc;
    __syncthreads();
    if (threadIdx.x < 16) {
        float a = 0.f;
        #pragma unroll
        for (int i = 0; i < 16; ++i) a += red[i][threadIdx.x];
        out[g * 16 + threadIdx.x] = a;
    }
}

extern "C" void kernel_launch(void* const* d_in, const int* in_sizes, int n_in,
                              void* d_out, int out_size, void* d_ws, size_t ws_size,
                              hipStream_t stream) {
    const float* x = (const float*)d_in[0];   // (1, 20) f32
    const float* w = (const float*)d_in[1];   // (60,)   f32
    float* out = (float*)d_out;               // (1, 1024) f32

    // Compose the CNOT block into 20 GF(2) row-masks over the index bits.
    // state_after[y] = state_enc[B y]; reverse-order rule: M[target] ^= M[control].
    MaskArg ma;
    {
        uint32_t M[NQ];
        for (int q = 0; q < NQ; ++q) M[q] = 1u << q;
        for (int q = NQ - 1; q >= 0; --q) {
            M[(q + 2) % NQ] ^= M[q];
            M[(q + 1) % NQ] ^= M[q];
        }
        for (int q = 0; q < NQ; ++q) {        // qubit j -> index bit (19-j)
            uint32_t im = 0;
            for (int j = 0; j < NQ; ++j)
                if ((M[q] >> j) & 1) im |= 1u << (NQ - 1 - j);
            ma.m[q] = im;
        }
        // host-computed parity of the (wq,r) fields: y = (wq<<18)|(r<<16)
        for (int k = 0; k < 16; ++k) {
            uint32_t y = ((uint32_t)(k >> 2) << 18) | ((uint32_t)(k & 3) << 16);
            uint32_t t = 0;
            for (int q = 0; q < NQ; ++q)
                t |= (uint32_t)(__builtin_popcount(ma.m[q] & y) & 1) << q;
            ma.thi[k] = t;
        }
    }

    qulinear_kernel<<<NH, BLOCK, 0, stream>>>(x, w, (float*)d_ws, ma);
    reduce_kernel<<<NH / 16, BLOCK, 0, stream>>>((const float*)d_ws, out);
}

// Round 5
// 65.427 us; speedup vs baseline: 1.0298x; 1.0044x over previous
//
#include <hip/hip_runtime.h>
#include <cstdint>

// QuLinear: 20-qubit circuit -> marginal probs of 10 MSB qubits (1024 floats).
//
// Round-7: kernel1 untouched (verified R4/65.7us version — R4 proved it's
// latency-bound, not VALU-bound: a 25% VALU cut moved only 0.4us).
// This round rebuilds kernel2, the last unmeasured piece of the ~25us
// non-fill budget:
//   old: 64 blocks x 256 thr (16K threads), 64 scalar 4B column loads each
//        -> latency-exposed (L3/HBM after dispatch boundary), ~3us model.
//   new: 64 blocks x 1024 thr (64K threads), 4 float4 loads each (same 4MB),
//        in-wave shfl_xor butterfly over row-groups, 256B LDS combine,
//        float4 stores. One latency round instead of ~4-8, 4x the waves.
//
// Kernel1 structure (verified): 4 waves per l-value, 4 amps/lane;
//   psi(h,l) = prod_q v_q[parity(mask_q & y)], y=(h<<10)|l; CNOT block is
//   GF(2)-linear, composed on host into 20 row-masks. Parity factorized
//   over disjoint y-fields (SALU l-part ^ LDS lane-table ^ kernarg hi-table).
//   Quad tables Q[g][16] give amp[r] = prod of 5 indexed LDS reads.
//   Butterfly over h: 6 shfl stages + 2 in-reg stages + fused 4x4 LDS
//   cross-wave combine. Block stores its own 1024-float row (no atomics).

#define NQ      20
#define NPART   10
#define NH      1024
#define BLOCK   256
#define NQUAD   5

struct MaskArg {
    uint32_t m[NQ];      // GF(2) row-masks over index bits
    uint32_t thi[16];    // parity of m[q] & ((wq<<18)|(r<<16)), idx = wq*4+r
};

__device__ __forceinline__ float2 cmul(float2 a, float2 b) {
    return make_float2(fmaf(a.x, b.x, -a.y * b.y), fmaf(a.x, b.y, a.y * b.x));
}
__device__ __forceinline__ float2 cadd(float2 a, float2 b) {
    return make_float2(a.x + b.x, a.y + b.y);
}

__global__ __launch_bounds__(BLOCK, 4) void qulinear_kernel(
        const float* __restrict__ x, const float* __restrict__ w,
        float* __restrict__ ws, MaskArg masks) {
    __shared__ float2 v[NQ][2];          // per-qubit encoding 2-vectors
    __shared__ float2 U[NPART][2][2];    // Rx*Rz*Rx for measured qubits
    __shared__ float2 Q[NQUAD][16];      // 4-qubit product tables (640 B)
    __shared__ uint32_t Tl[64];          // lane-field parity table (256 B)
    __shared__ float2 ex[4][4][64];      // cross-wave exchange (8 KB)

    const int tid = threadIdx.x;

    // ---- block setup: wave 0 builds v,U; wave 1 builds Tl ----
    if (tid < NQ) {
        float xq = x[tid];
        float th = atanf(xq);
        float ph = atanf(xq * xq);
        float c, s, cp, sp;
        __sincosf(0.5f * th, &s, &c);
        __sincosf(0.5f * ph, &sp, &cp);
        float a = (c - s) * 0.70710678118654752f;
        float b = (c + s) * 0.70710678118654752f;
        v[tid][0] = make_float2(a * cp, -a * sp);
        v[tid][1] = make_float2(b * cp,  b * sp);
    }
    if (tid < NPART) {
        const float WM = 0.63245553203367590f;   // sqrt(2/5)
        float a0 = w[3 * tid + 0] * WM;
        float a1 = w[3 * tid + 1] * WM;
        float a2 = w[3 * tid + 2] * WM;
        float c0, s0, c1, s1, c2, s2;
        __sincosf(0.5f * a0, &s0, &c0);
        __sincosf(0.5f * a1, &s1, &c1);
        __sincosf(0.5f * a2, &s2, &c2);
        float2 e0 = make_float2(c1, -s1), e1 = make_float2(c1, s1);
        float2 m00 = cmul(e0, make_float2(c0, 0.f));
        float2 m01 = cmul(e0, make_float2(0.f, -s0));
        float2 m10 = cmul(e1, make_float2(0.f, -s0));
        float2 m11 = cmul(e1, make_float2(c0, 0.f));
        float2 r00 = make_float2(c2, 0.f), r01 = make_float2(0.f, -s2);
        U[tid][0][0] = cadd(cmul(r00, m00), cmul(r01, m10));
        U[tid][0][1] = cadd(cmul(r00, m01), cmul(r01, m11));
        U[tid][1][0] = cadd(cmul(r01, m00), cmul(r00, m10));
        U[tid][1][1] = cadd(cmul(r01, m01), cmul(r00, m11));
    }
    if (tid >= 64 && tid < 128) {
        const uint32_t yl = (uint32_t)(tid - 64) << NPART;   // lane field
        uint32_t t = 0;
        #pragma unroll
        for (int q = 0; q < NQ; ++q)
            t |= (uint32_t)(__popc(masks.m[q] & yl) & 1) << q;
        Tl[tid - 64] = t;
    }
    __syncthreads();
    if (tid < 16 * NQUAD) {
        int g = tid >> 4, j = tid & 15;   // bit i of j selects qubit 4g+i
        Q[g][j] = cmul(cmul(v[4 * g + 0][j & 1],        v[4 * g + 1][(j >> 1) & 1]),
                       cmul(v[4 * g + 2][(j >> 2) & 1], v[4 * g + 3][(j >> 3) & 1]));
    }
    __syncthreads();

    const int wq   = tid >> 6;           // wave index = h-bits 8..9
    const int lane = tid & 63;           // h-bits 0..5
    const uint32_t l = blockIdx.x;

    // ---- parity words via factorized tables ----
    // block-uniform l-field parity (all inputs SGPR -> scalarizable)
    uint32_t tl = 0;
    #pragma unroll
    for (int q = 0; q < NQ; ++q)
        tl |= (uint32_t)(__popc(masks.m[q] & l) & 1) << q;

    const uint32_t sbase = tl ^ Tl[lane];
    uint32_t s[4];
    #pragma unroll
    for (int r = 0; r < 4; ++r)
        s[r] = sbase ^ masks.thi[(wq << 2) | r];

    // ---- wave-uniform row of the 4x4 cross-wave matrix G = U0 (x) U1 ----
    float2 g[4];
    #pragma unroll
    for (int j = 0; j < 4; ++j)
        g[j] = cmul(U[0][wq >> 1][j >> 1], U[1][wq & 1][j & 1]);

    // ---- synthesize psi via quad tables: amp[r] = prod_g Q[g][4-bit sel] ----
    float2 amp[4];
    #pragma unroll
    for (int r = 0; r < 4; ++r) amp[r] = Q[0][s[r] & 15];

    #pragma unroll
    for (int p = 1; p < NQUAD; ++p) {
        #pragma unroll
        for (int r = 0; r < 4; ++r) {
            int idx = (s[r] >> (4 * p)) & 15;
            amp[r] = cmul(amp[r], Q[p][idx]);
        }
    }

    // ---- in-register stages: h-bit 6 (U[3]), h-bit 7 (U[2]) ----
    {
        float2 g00 = U[3][0][0], g01 = U[3][0][1], g10 = U[3][1][0], g11 = U[3][1][1];
        float2 a, b;
        a = amp[0]; b = amp[1];
        amp[0] = cadd(cmul(g00, a), cmul(g01, b));
        amp[1] = cadd(cmul(g10, a), cmul(g11, b));
        a = amp[2]; b = amp[3];
        amp[2] = cadd(cmul(g00, a), cmul(g01, b));
        amp[3] = cadd(cmul(g10, a), cmul(g11, b));
    }
    {
        float2 g00 = U[2][0][0], g01 = U[2][0][1], g10 = U[2][1][0], g11 = U[2][1][1];
        float2 a, b;
        a = amp[0]; b = amp[2];
        amp[0] = cadd(cmul(g00, a), cmul(g01, b));
        amp[2] = cadd(cmul(g10, a), cmul(g11, b));
        a = amp[1]; b = amp[3];
        amp[1] = cadd(cmul(g00, a), cmul(g01, b));
        amp[3] = cadd(cmul(g10, a), cmul(g11, b));
    }

    // ---- shfl stages: h-bits 0..5 (U[9]..U[4]) ----
    #pragma unroll
    for (int p = 0; p < 6; ++p) {
        const int lm = 1 << p;
        const bool bit = (lane & lm) != 0;
        float2 g00 = U[9 - p][0][0], g01 = U[9 - p][0][1];
        float2 g10 = U[9 - p][1][0], g11 = U[9 - p][1][1];
        float2 ga = bit ? g11 : g00;
        float2 gb = bit ? g10 : g01;
        #pragma unroll
        for (int r = 0; r < 4; ++r) {
            float2 mine = amp[r];
            float2 oth = make_float2(__shfl_xor(mine.x, lm, 64),
                                     __shfl_xor(mine.y, lm, 64));
            amp[r] = cadd(cmul(ga, mine), cmul(gb, oth));
        }
    }

    // ---- cross-wave stage: h-bits 8..9 via fused 4x4 LDS combine ----
    #pragma unroll
    for (int r = 0; r < 4; ++r) ex[wq][r][lane] = amp[r];
    __syncthreads();
    #pragma unroll
    for (int r = 0; r < 4; ++r) {
        float2 acc = cmul(g[0], ex[0][r][lane]);
        acc = cadd(acc, cmul(g[1], ex[1][r][lane]));
        acc = cadd(acc, cmul(g[2], ex[2][r][lane]));
        acc = cadd(acc, cmul(g[3], ex[3][r][lane]));
        amp[r] = acc;
    }

    // ---- |amp|^2 -> this block's own row (plain coalesced stores) ----
    float* wsp = ws + (size_t)blockIdx.x * NH;
    #pragma unroll
    for (int r = 0; r < 4; ++r) {
        int h = (wq << 8) | (r << 6) | lane;
        wsp[h] = fmaf(amp[r].x, amp[r].x, amp[r].y * amp[r].y);
    }
}

// Column-reduce 1024 rows of ws into out.
// 64 blocks x 1024 threads. ws viewed as [1024 rows][256 float4-cols];
// block g owns float4-cols g*4..g*4+3 (h = g*16..g*16+15).
// thread t: c4 = t&3 (float4-col), rg = t>>2 (256 row-groups of 4 rows)
//   -> 4 coalesced float4 loads, shfl_xor butterfly over lane bits 2..5
//      (16 row-groups per wave), 16 wave-partials -> LDS -> 4 float4 stores.
__global__ __launch_bounds__(1024) void reduce_kernel(
        const float4* __restrict__ ws4, float4* __restrict__ out4) {
    __shared__ float4 red[16][4];
    const int t  = threadIdx.x;
    const int g  = blockIdx.x;
    const int c4 = t & 3;
    const int rg = t >> 2;               // 0..255
    const float4* p = ws4 + (size_t)(rg * 4) * (NH / 4) + g * 4 + c4;
    float4 a0 = p[0];
    float4 a1 = p[NH / 4];
    float4 a2 = p[2 * (NH / 4)];
    float4 a3 = p[3 * (NH / 4)];
    float4 acc = make_float4(a0.x + a1.x + a2.x + a3.x,
                             a0.y + a1.y + a2.y + a3.y,
                             a0.z + a1.z + a2.z + a3.z,
                             a0.w + a1.w + a2.w + a3.w);
    // butterfly over the 16 row-groups within this wave (lane bits 2..5)
    #pragma unroll
    for (int m = 4; m <= 32; m <<= 1) {
        acc.x += __shfl_xor(acc.x, m, 64);
        acc.y += __shfl_xor(acc.y, m, 64);
        acc.z += __shfl_xor(acc.z, m, 64);
        acc.w += __shfl_xor(acc.w, m, 64);
    }
    const int wave = t >> 6;
    if ((t & 63) < 4) red[wave][c4] = acc;   // lanes 0..3 carry c4 0..3
    __syncthreads();
    if (t < 4) {
        float4 s = red[0][t];
        #pragma unroll
        for (int i = 1; i < 16; ++i) {
            s.x += red[i][t].x; s.y += red[i][t].y;
            s.z += red[i][t].z; s.w += red[i][t].w;
        }
        out4[g * 4 + t] = s;
    }
}

extern "C" void kernel_launch(void* const* d_in, const int* in_sizes, int n_in,
                              void* d_out, int out_size, void* d_ws, size_t ws_size,
                              hipStream_t stream) {
    const float* x = (const float*)d_in[0];   // (1, 20) f32
    const float* w = (const float*)d_in[1];   // (60,)   f32
    float* out = (float*)d_out;               // (1, 1024) f32

    // Compose the CNOT block into 20 GF(2) row-masks over the index bits.
    // state_after[y] = state_enc[B y]; reverse-order rule: M[target] ^= M[control].
    MaskArg ma;
    {
        uint32_t M[NQ];
        for (int q = 0; q < NQ; ++q) M[q] = 1u << q;
        for (int q = NQ - 1; q >= 0; --q) {
            M[(q + 2) % NQ] ^= M[q];
            M[(q + 1) % NQ] ^= M[q];
        }
        for (int q = 0; q < NQ; ++q) {        // qubit j -> index bit (19-j)
            uint32_t im = 0;
            for (int j = 0; j < NQ; ++j)
                if ((M[q] >> j) & 1) im |= 1u << (NQ - 1 - j);
            ma.m[q] = im;
        }
        // host-computed parity of the (wq,r) fields: y = (wq<<18)|(r<<16)
        for (int k = 0; k < 16; ++k) {
            uint32_t y = ((uint32_t)(k >> 2) << 18) | ((uint32_t)(k & 3) << 16);
            uint32_t t = 0;
            for (int q = 0; q < NQ; ++q)
                t |= (uint32_t)(__builtin_popcount(ma.m[q] & y) & 1) << q;
            ma.thi[k] = t;
        }
    }

    qulinear_kernel<<<NH, BLOCK, 0, stream>>>(x, w, (float*)d_ws, ma);
    reduce_kernel<<<64, 1024, 0, stream>>>((const float4*)d_ws, (float4*)out);
}